// Round 11
// baseline (111.597 us; speedup 1.0000x reference)
//
#include <hip/hip_runtime.h>

#define B_ROWS 16384
#define I_DIM  512
#define O_DIM  64
#define NFEAT  8          // 2*K fourier features per x element
// W2t: [I_DIM][O_DIM][NFEAT] f16  (512 KB)   at d_ws + 0
// cst: [O_DIM] f32                           at d_ws + W2_BYTES
#define W2_BYTES ((size_t)I_DIM * O_DIM * NFEAT * 2)

typedef _Float16 f16x8 __attribute__((ext_vector_type(8)));
typedef float    f32x4 __attribute__((ext_vector_type(4)));

// ---------------- prep: W2[i*8+f][o] = w[o,i]*coef[o,i,f+1], f16 ----------------
// t = o*512 + i  (i fastest): w[t] coalesced, coef+t*9 contiguous across wave.
// Write w2[(i*64+o)*8] scattered (16B per 1KB) — only 512KB total, L2 absorbs.
__global__ __launch_bounds__(256) void prep_w2(const float* __restrict__ w,
                                               const float* __restrict__ coef,
                                               _Float16* __restrict__ w2) {
    int t = blockIdx.x * 256 + threadIdx.x;   // 0..32767
    int o = t >> 9;
    int i = t & 511;
    float wv = w[t];
    const float* cp = coef + (size_t)t * 9;
    f16x8 v;
#pragma unroll
    for (int f = 0; f < 8; ++f) v[f] = (_Float16)(wv * cp[f + 1]);   // RTN casts
    *reinterpret_cast<f16x8*>(w2 + ((size_t)(i * 64 + o)) * 8) = v;
}

// ---------------- prep: const[o] = sum_i w[o,i]*coef[o,i,0] ----------------
__global__ __launch_bounds__(256) void prep_const(const float* __restrict__ w,
                                                  const float* __restrict__ coef,
                                                  float* __restrict__ cst) {
    int o = blockIdx.x;
    int t = threadIdx.x;
    float s = 0.f;
#pragma unroll
    for (int i = t; i < I_DIM; i += 256)
        s += w[o * I_DIM + i] * coef[((size_t)(o * I_DIM + i)) * 9];
#pragma unroll
    for (int off = 32; off; off >>= 1) s += __shfl_down(s, off, 64);
    __shared__ float ps[4];
    if ((t & 63) == 0) ps[t >> 6] = s;
    __syncthreads();
    if (t == 0) cst[o] = ps[0] + ps[1] + ps[2] + ps[3];
}

// ---------------- main: out[64 rows x 64 cols] per block ----------------
// 512 threads = 8 waves, 1 block/CU (128KB LDS). Pipelined T14-style:
// prologue issues ALL 16 tile loads to registers; per m-tile pass we ds_write
// only that pass's 4 float4s (rows 16m..16m+15), barrier, compute its 16
// K-steps — remaining global loads stay in flight across the barrier
// (compiler-derived counted vmcnt from the data dep; no inline asm).
// Race-freedom: pass m reads rows 16m..+15 only; concurrent writes target
// rows 16(m+1).. — disjoint. Worst case (compiler drains at barrier) ==
// the previous serial schedule.
__global__ __launch_bounds__(512, 2) void fourier_main(const float* __restrict__ x,
                                                       const _Float16* __restrict__ w2,
                                                       const float* __restrict__ cst,
                                                       float* __restrict__ out) {
    __shared__ __align__(16) float xs[64][512];                      // 128 KB
    float (*red)[64][65] = reinterpret_cast<float(*)[64][65]>(&xs[0][0]); // 65 KB alias

    const int tid   = threadIdx.x;
    const int wave  = tid >> 6;
    const int lane  = tid & 63;
    const int col16 = lane & 15;   // A-row within tile / B,D column
    const int ig    = lane >> 4;   // i sub-offset 0..3 (k-chunk of fragment)
    const int rbase = blockIdx.x * 64;
    const int i0    = wave * 64;   // this wave's K-slice (64 i's = 512 k's)

    // ---- prologue: issue all 16 coalesced tile loads (1KB/wave-instr) ----
    const float4* xg = reinterpret_cast<const float4*>(x + (size_t)rbase * I_DIM);
    float4 xv16[16];
#pragma unroll
    for (int j = 0; j < 16; ++j) xv16[j] = xg[j * 512 + tid];

    f32x4 acc[4][4] = {};          // [mtile][ntile], f32 accum
    const f16x8* __restrict__ bbase = reinterpret_cast<const f16x8*>(w2);

#pragma unroll
    for (int m = 0; m < 4; ++m) {
        // ---- write this pass's row group (rows 16m..16m+15, 32 KB) ----
#pragma unroll
        for (int jj = 0; jj < 4; ++jj) {
            const int j  = m * 4 + jj;
            const int f4 = j * 512 + tid;     // f4>>7 in [16m,16m+16)
            *reinterpret_cast<float4*>(&xs[f4 >> 7][(f4 & 127) << 2]) = xv16[j];
        }
        __syncthreads();                      // group m visible to all waves

        // ---- compute pass m: 16 K-steps over this wave's K-slice ----
        f16x8 bf[4], bn[4];
        {
            const int i = i0 + ig;
#pragma unroll
            for (int n = 0; n < 4; ++n) bf[n] = bbase[i * 64 + n * 16 + col16];
        }
        for (int s = 0; s < 16; ++s) {
            const int i = i0 + s * 4 + ig;
            if (s < 15) {
                const int i2 = i + 4;
#pragma unroll
                for (int n = 0; n < 4; ++n) bn[n] = bbase[i2 * 64 + n * 16 + col16];
            }
            const float xv = xs[m * 16 + col16][i];   // broadcast within 16-lane grp
            float s1, c1;
            __sincosf(xv, &s1, &c1);
            const float tc = 2.f * c1;
            const float s2 = tc * s1;          // sin2
            const float c2 = tc * c1 - 1.f;    // cos2
            const float s3 = tc * s2 - s1;     // sin3
            const float c3 = tc * c2 - c1;     // cos3
            const float s4 = tc * s3 - s2;     // sin4
            const float c4 = tc * c3 - c2;     // cos4
            f16x8 af;
            af[0] = (_Float16)s1; af[1] = (_Float16)c1;   // RTN casts
            af[2] = (_Float16)s2; af[3] = (_Float16)c2;
            af[4] = (_Float16)s3; af[5] = (_Float16)c3;
            af[6] = (_Float16)s4; af[7] = (_Float16)c4;
#pragma unroll
            for (int n = 0; n < 4; ++n)
                acc[m][n] = __builtin_amdgcn_mfma_f32_16x16x32_f16(af, bf[n], acc[m][n], 0, 0, 0);
#pragma unroll
            for (int n = 0; n < 4; ++n) bf[n] = bn[n];
        }
        // no trailing barrier: next pass writes rows 16(m+1).. (disjoint from
        // any rows still being read); its __syncthreads orders write->read.
    }

    // ---- epilogue: 8 K-slices -> 4 LDS slices -> sum + const -> out ----
    // D layout: within-tile row = ig*4 + q, col = col16.
    __syncthreads();               // xs dead; safe to overwrite as red
    if (wave < 4) {
#pragma unroll
        for (int m = 0; m < 4; ++m)
#pragma unroll
            for (int n = 0; n < 4; ++n)
#pragma unroll
                for (int q = 0; q < 4; ++q)
                    red[wave][m * 16 + ig * 4 + q][n * 16 + col16] = acc[m][n][q];
    }
    __syncthreads();
    if (wave >= 4) {
#pragma unroll
        for (int m = 0; m < 4; ++m)
#pragma unroll
            for (int n = 0; n < 4; ++n)
#pragma unroll
                for (int q = 0; q < 4; ++q)
                    red[wave - 4][m * 16 + ig * 4 + q][n * 16 + col16] += acc[m][n][q];
    }
    __syncthreads();

    const float cv = cst[lane];            // out column = lane
#pragma unroll
    for (int j = 0; j < 8; ++j) {
        const int r = wave + 8 * j;        // rows 0..63
        float v = cv + red[0][r][lane] + red[1][r][lane] + red[2][r][lane] + red[3][r][lane];
        out[(size_t)(rbase + r) * 64 + lane] = v;   // wave writes 256B contiguous
    }
}

extern "C" void kernel_launch(void* const* d_in, const int* in_sizes, int n_in,
                              void* d_out, int out_size, void* d_ws, size_t ws_size,
                              hipStream_t stream) {
    const float* x    = (const float*)d_in[0];
    const float* w    = (const float*)d_in[1];
    const float* coef = (const float*)d_in[2];
    _Float16* w2  = (_Float16*)d_ws;
    float*    cst = (float*)((char*)d_ws + W2_BYTES);
    float*    out = (float*)d_out;

    hipLaunchKernelGGL(prep_w2,    dim3(128), dim3(256), 0, stream, w, coef, w2);
    hipLaunchKernelGGL(prep_const, dim3(64),  dim3(256), 0, stream, w, coef, cst);
    hipLaunchKernelGGL(fourier_main, dim3(B_ROWS / 64), dim3(512), 0, stream, x, w2, cst, out);
}

// Round 12
// 93.242 us; speedup vs baseline: 1.1969x; 1.1969x over previous
//
#include <hip/hip_runtime.h>

#define B_ROWS 16384
#define I_DIM  512
#define O_DIM  64
#define NFEAT  8          // 2*K fourier features per x element
#define XPAD   516        // LDS row stride in floats; 516%32==4 -> column reads
                          // spread 16-lane groups over 8 banks (2-way = free)
// W2t: [I_DIM][O_DIM][NFEAT] f16  (512 KB)   at d_ws + 0
// cst: [O_DIM] f32                           at d_ws + W2_BYTES
#define W2_BYTES ((size_t)I_DIM * O_DIM * NFEAT * 2)

typedef _Float16 f16x8 __attribute__((ext_vector_type(8)));
typedef float    f32x4 __attribute__((ext_vector_type(4)));

// ---------------- prep: W2[i*8+f][o] = w[o,i]*coef[o,i,f+1], f16 ----------------
__global__ __launch_bounds__(256) void prep_w2(const float* __restrict__ w,
                                               const float* __restrict__ coef,
                                               _Float16* __restrict__ w2) {
    int t = blockIdx.x * 256 + threadIdx.x;   // 0..32767 ; t = o*512 + i
    int o = t >> 9;
    int i = t & 511;
    float wv = w[t];
    const float* cp = coef + (size_t)t * 9;
    f16x8 v;
#pragma unroll
    for (int f = 0; f < 8; ++f) v[f] = (_Float16)(wv * cp[f + 1]);   // RTN casts
    *reinterpret_cast<f16x8*>(w2 + ((size_t)(i * 64 + o)) * 8) = v;
}

// ---------------- prep: const[o] = sum_i w[o,i]*coef[o,i,0] ----------------
__global__ __launch_bounds__(256) void prep_const(const float* __restrict__ w,
                                                  const float* __restrict__ coef,
                                                  float* __restrict__ cst) {
    int o = blockIdx.x;
    int t = threadIdx.x;
    float s = 0.f;
#pragma unroll
    for (int i = t; i < I_DIM; i += 256)
        s += w[o * I_DIM + i] * coef[((size_t)(o * I_DIM + i)) * 9];
#pragma unroll
    for (int off = 32; off; off >>= 1) s += __shfl_down(s, off, 64);
    __shared__ float ps[4];
    if ((t & 63) == 0) ps[t >> 6] = s;
    __syncthreads();
    if (t == 0) cst[o] = ps[0] + ps[1] + ps[2] + ps[3];
}

// ---------------- main: out[64 rows x 64 cols] per block ----------------
// 512 threads = 8 waves, 1 block/CU (132KB LDS). R11 post-mortem fixes:
//  * no register staging (VGPR=88 + WRITE 36MB proved xv16 spilled to scratch)
//    -> direct load->ds_write, 16 coalesced float4 loads in flight per wave.
//  * XPAD=516 (SQ_LDS_BANK_CONFLICT=4.3M proved the column read
//    xs[m*16+col16][i] is a 16-way same-bank conflict at stride 512)
//  * amdgpu_waves_per_eu(2,2): LDS caps occupancy at 2 waves/EU anyway; pinning
//    gives the allocator the full 256-VGPR budget so nothing ever spills.
//  * s-outer/m-inner (4 independent sincos->MFMA chains of ILP; B fragments
//    read exactly once per wave).
__global__ __launch_bounds__(512)
__attribute__((amdgpu_waves_per_eu(2, 2)))
void fourier_main(const float* __restrict__ x,
                  const _Float16* __restrict__ w2,
                  const float* __restrict__ cst,
                  float* __restrict__ out) {
    __shared__ __align__(16) float xs[64][XPAD];                     // 132096 B
    float (*red)[64][65] = reinterpret_cast<float(*)[64][65]>(&xs[0][0]); // 65KB alias

    const int tid   = threadIdx.x;
    const int wave  = tid >> 6;
    const int lane  = tid & 63;
    const int col16 = lane & 15;   // A-row within tile / B,D column
    const int ig    = lane >> 4;   // i sub-offset 0..3 (k-chunk of fragment)
    const int rbase = blockIdx.x * 64;
    const int i0    = wave * 64;   // this wave's K-slice (64 i's = 512 k's)

    // ---- phase 1: stage x (64 rows x 512 f32), coalesced, no reg staging ----
    {
        const float4* xg = reinterpret_cast<const float4*>(x + (size_t)rbase * I_DIM);
#pragma unroll
        for (int j = 0; j < 16; ++j) {
            int f4   = j * 512 + tid;         // wave reads 1KB contiguous per j
            float4 v = xg[f4];
            *reinterpret_cast<float4*>(&xs[f4 >> 7][(f4 & 127) << 2]) = v;
        }
    }
    __syncthreads();

    // ---- phase 2: MFMA main loop (s outer, m inner) ----
    f32x4 acc[4][4] = {};          // [mtile][ntile], f32 accum
    const f16x8* __restrict__ bbase = reinterpret_cast<const f16x8*>(w2);

    f16x8 bf[4], bn[4];
    {
        const int i = i0 + ig;
#pragma unroll
        for (int n = 0; n < 4; ++n) bf[n] = bbase[i * 64 + n * 16 + col16];
    }

    for (int s = 0; s < 16; ++s) {
        const int i = i0 + s * 4 + ig;

        if (s < 15) {
            const int i2 = i + 4;
#pragma unroll
            for (int n = 0; n < 4; ++n) bn[n] = bbase[i2 * 64 + n * 16 + col16];
        }

        float xv[4];
#pragma unroll
        for (int m = 0; m < 4; ++m) xv[m] = xs[m * 16 + col16][i];  // 2-way: free

#pragma unroll
        for (int m = 0; m < 4; ++m) {
            float s1, c1;
            __sincosf(xv[m], &s1, &c1);
            const float tc = 2.f * c1;
            const float s2 = tc * s1;          // sin2
            const float c2 = tc * c1 - 1.f;    // cos2
            const float s3 = tc * s2 - s1;     // sin3
            const float c3 = tc * c2 - c1;     // cos3
            const float s4 = tc * s3 - s2;     // sin4
            const float c4 = tc * c3 - c2;     // cos4
            f16x8 af;
            af[0] = (_Float16)s1; af[1] = (_Float16)c1;   // RTN casts
            af[2] = (_Float16)s2; af[3] = (_Float16)c2;
            af[4] = (_Float16)s3; af[5] = (_Float16)c3;
            af[6] = (_Float16)s4; af[7] = (_Float16)c4;
#pragma unroll
            for (int n = 0; n < 4; ++n)
                acc[m][n] = __builtin_amdgcn_mfma_f32_16x16x32_f16(af, bf[n], acc[m][n], 0, 0, 0);
        }

#pragma unroll
        for (int n = 0; n < 4; ++n) bf[n] = bn[n];
    }

    // ---- phase 3: 8 K-slices -> 4 LDS slices -> sum + const -> out ----
    // D layout: within-tile row = ig*4 + q, col = col16.
    __syncthreads();               // xs dead; safe to overwrite as red
    if (wave < 4) {
#pragma unroll
        for (int m = 0; m < 4; ++m)
#pragma unroll
            for (int n = 0; n < 4; ++n)
#pragma unroll
                for (int q = 0; q < 4; ++q)
                    red[wave][m * 16 + ig * 4 + q][n * 16 + col16] = acc[m][n][q];
    }
    __syncthreads();
    if (wave >= 4) {
#pragma unroll
        for (int m = 0; m < 4; ++m)
#pragma unroll
            for (int n = 0; n < 4; ++n)
#pragma unroll
                for (int q = 0; q < 4; ++q)
                    red[wave - 4][m * 16 + ig * 4 + q][n * 16 + col16] += acc[m][n][q];
    }
    __syncthreads();

    const float cv = cst[lane];            // out column = lane
#pragma unroll
    for (int j = 0; j < 8; ++j) {
        const int r = wave + 8 * j;        // rows 0..63
        float v = cv + red[0][r][lane] + red[1][r][lane] + red[2][r][lane] + red[3][r][lane];
        out[(size_t)(rbase + r) * 64 + lane] = v;   // wave writes 256B contiguous
    }
}

extern "C" void kernel_launch(void* const* d_in, const int* in_sizes, int n_in,
                              void* d_out, int out_size, void* d_ws, size_t ws_size,
                              hipStream_t stream) {
    const float* x    = (const float*)d_in[0];
    const float* w    = (const float*)d_in[1];
    const float* coef = (const float*)d_in[2];
    _Float16* w2  = (_Float16*)d_ws;
    float*    cst = (float*)((char*)d_ws + W2_BYTES);
    float*    out = (float*)d_out;

    hipLaunchKernelGGL(prep_w2,    dim3(128), dim3(256), 0, stream, w, coef, w2);
    hipLaunchKernelGGL(prep_const, dim3(64),  dim3(256), 0, stream, w, coef, cst);
    hipLaunchKernelGGL(fourier_main, dim3(B_ROWS / 64), dim3(512), 0, stream, x, w2, cst, out);
}

// Round 14
// 90.281 us; speedup vs baseline: 1.2361x; 1.0328x over previous
//
#include <hip/hip_runtime.h>

#define B_ROWS 16384
#define I_DIM  512
#define O_DIM  64
#define NFEAT  8          // 2*K fourier features per x element
#define TROWS  32         // b-rows per block (66KB LDS -> 2 blocks/CU)
#define XPAD   516        // LDS row stride in floats; 516%32==4 -> column reads 2-way (free)
// W2t: [I_DIM][O_DIM][NFEAT] f16  (512 KB)   at d_ws + 0
// cst: [O_DIM] f32                           at d_ws + W2_BYTES
#define W2_BYTES ((size_t)I_DIM * O_DIM * NFEAT * 2)

typedef _Float16 f16x8 __attribute__((ext_vector_type(8)));
typedef float    f32x4 __attribute__((ext_vector_type(4)));

// ---------------- fused prep: W2 + const, one launch ----------------
// Block o (64 blocks x 256 threads): thread t handles i = t and t+256.
// Reads w[o*512+i] coalesced, coef[(o*512+i)*9..] contiguous across wave.
// W2[(i*64+o)*8] scattered 16B stores (512KB total, L2 absorbs).
// cst[o] = sum_i w[o,i]*coef[o,i,0] via shfl + LDS reduce.
__global__ __launch_bounds__(256) void prep(const float* __restrict__ w,
                                            const float* __restrict__ coef,
                                            _Float16* __restrict__ w2,
                                            float* __restrict__ cst) {
    const int o = blockIdx.x;
    const int t = threadIdx.x;
    float csum = 0.f;
#pragma unroll
    for (int ii = 0; ii < 2; ++ii) {
        const int i   = ii * 256 + t;
        const int idx = o * I_DIM + i;
        const float wv = w[idx];
        const float* cp = coef + (size_t)idx * 9;
        csum += wv * cp[0];
        f16x8 v;
#pragma unroll
        for (int f = 0; f < 8; ++f) v[f] = (_Float16)(wv * cp[f + 1]);   // RTN
        *reinterpret_cast<f16x8*>(w2 + ((size_t)(i * 64 + o)) * 8) = v;
    }
#pragma unroll
    for (int off = 32; off; off >>= 1) csum += __shfl_down(csum, off, 64);
    __shared__ float ps[4];
    if ((t & 63) == 0) ps[t >> 6] = csum;
    __syncthreads();
    if (t == 0) cst[o] = ps[0] + ps[1] + ps[2] + ps[3];
}

// ---------------- main: out[32 rows x 64 cols] per block ----------------
// 512 threads = 8 waves, 66KB LDS -> 2 blocks/CU (4 waves/SIMD): block-level
// overlap of staging (HBM) with compute (VALU/MFMA) via occupancy.
// Trig: hardware v_sin/v_cos on fract(x/2pi) (v_sin takes REVOLUTIONS per
// ISA; exact by periodicity; ~1e-6 abs err << f16 quantization) replaces
// OCML sincos (~30 VALU ops -> 4).
// Wave w owns K-slice i in [w*64, w*64+64); m in {0,1} (rows m*16+col16).
__global__ __launch_bounds__(512)
__attribute__((amdgpu_waves_per_eu(4, 4)))   // pin: full 128-VGPR budget, no spill
void fourier_main(const float* __restrict__ x,
                  const _Float16* __restrict__ w2,
                  const float* __restrict__ cst,
                  float* __restrict__ out) {
    __shared__ __align__(16) float xs[TROWS][XPAD];                  // 66048 B
    float (*red)[TROWS][65] = reinterpret_cast<float(*)[TROWS][65]>(&xs[0][0]); // 33KB alias

    const int tid   = threadIdx.x;
    const int wave  = tid >> 6;
    const int lane  = tid & 63;
    const int col16 = lane & 15;   // A-row within tile / B,D column
    const int ig    = lane >> 4;   // i sub-offset 0..3 (k-chunk of fragment)
    const int rbase = blockIdx.x * TROWS;
    const int i0    = wave * 64;   // this wave's K-slice (64 i's = 512 k's)

    // ---- phase 1: stage x (32 rows x 512 f32 = 64KB), coalesced ----
    {
        const float4* xg = reinterpret_cast<const float4*>(x + (size_t)rbase * I_DIM);
#pragma unroll
        for (int j = 0; j < 8; ++j) {
            int f4   = j * 512 + tid;         // wave reads 1KB contiguous per j
            float4 v = xg[f4];
            *reinterpret_cast<float4*>(&xs[f4 >> 7][(f4 & 127) << 2]) = v;
        }
    }
    __syncthreads();

    // ---- phase 2: MFMA main loop (s outer, m inner) ----
    f32x4 acc[2][4] = {};          // [mtile][ntile], f32 accum
    const f16x8* __restrict__ bbase = reinterpret_cast<const f16x8*>(w2);
    const float RINV = 0.15915494309189535f;   // 1/(2*pi)

    f16x8 bf[4], bn[4];
    {
        const int i = i0 + ig;
#pragma unroll
        for (int n = 0; n < 4; ++n) bf[n] = bbase[i * 64 + n * 16 + col16];
    }

    for (int s = 0; s < 16; ++s) {
        const int i = i0 + s * 4 + ig;

        if (s < 15) {
            const int i2 = i + 4;
#pragma unroll
            for (int n = 0; n < 4; ++n) bn[n] = bbase[i2 * 64 + n * 16 + col16];
        }

        float xv[2];
#pragma unroll
        for (int m = 0; m < 2; ++m) xv[m] = xs[m * 16 + col16][i];  // 2-way: free

#pragma unroll
        for (int m = 0; m < 2; ++m) {
            // sin(x), cos(x) via trans pipe: exact by periodicity of 2pi
            const float r  = __builtin_amdgcn_fractf(xv[m] * RINV);
            const float s1 = __builtin_amdgcn_sinf(r);
            const float c1 = __builtin_amdgcn_cosf(r);
            const float tc = 2.f * c1;
            const float s2 = tc * s1;          // sin2
            const float c2 = tc * c1 - 1.f;    // cos2
            const float s3 = tc * s2 - s1;     // sin3
            const float c3 = tc * c2 - c1;     // cos3
            const float s4 = tc * s3 - s2;     // sin4
            const float c4 = tc * c3 - c2;     // cos4
            f16x8 af;
            af[0] = (_Float16)s1; af[1] = (_Float16)c1;   // RTN casts
            af[2] = (_Float16)s2; af[3] = (_Float16)c2;
            af[4] = (_Float16)s3; af[5] = (_Float16)c3;
            af[6] = (_Float16)s4; af[7] = (_Float16)c4;
#pragma unroll
            for (int n = 0; n < 4; ++n)
                acc[m][n] = __builtin_amdgcn_mfma_f32_16x16x32_f16(af, bf[n], acc[m][n], 0, 0, 0);
        }

#pragma unroll
        for (int n = 0; n < 4; ++n) bf[n] = bn[n];
    }

    // ---- phase 3: 8 K-slices -> 4 LDS slices -> sum + const -> out ----
    // D layout: within-tile row = ig*4 + q, col = col16.
    __syncthreads();               // xs dead; safe to overwrite as red
    if (wave < 4) {
#pragma unroll
        for (int m = 0; m < 2; ++m)
#pragma unroll
            for (int n = 0; n < 4; ++n)
#pragma unroll
                for (int q = 0; q < 4; ++q)
                    red[wave][m * 16 + ig * 4 + q][n * 16 + col16] = acc[m][n][q];
    }
    __syncthreads();
    if (wave >= 4) {
#pragma unroll
        for (int m = 0; m < 2; ++m)
#pragma unroll
            for (int n = 0; n < 4; ++n)
#pragma unroll
                for (int q = 0; q < 4; ++q)
                    red[wave - 4][m * 16 + ig * 4 + q][n * 16 + col16] += acc[m][n][q];
    }
    __syncthreads();

    const float cv = cst[lane];            // out column = lane
#pragma unroll
    for (int j = 0; j < 4; ++j) {
        const int r = wave + 8 * j;        // rows 0..31
        float v = cv + red[0][r][lane] + red[1][r][lane] + red[2][r][lane] + red[3][r][lane];
        out[(size_t)(rbase + r) * 64 + lane] = v;   // wave writes 256B contiguous
    }
}

extern "C" void kernel_launch(void* const* d_in, const int* in_sizes, int n_in,
                              void* d_out, int out_size, void* d_ws, size_t ws_size,
                              hipStream_t stream) {
    const float* x    = (const float*)d_in[0];
    const float* w    = (const float*)d_in[1];
    const float* coef = (const float*)d_in[2];
    _Float16* w2  = (_Float16*)d_ws;
    float*    cst = (float*)((char*)d_ws + W2_BYTES);
    float*    out = (float*)d_out;

    hipLaunchKernelGGL(prep, dim3(O_DIM), dim3(256), 0, stream, w, coef, w2, cst);
    hipLaunchKernelGGL(fourier_main, dim3(B_ROWS / TROWS), dim3(512), 0, stream, x, w2, cst, out);
}